// Round 1
// baseline (282.535 us; speedup 1.0000x reference)
//
#include <hip/hip_runtime.h>

#define CC 192
#define NN 16384
#define TN 64
#define XST 104   // Xs LDS stride (elements): bank-start 20n%32 -> conflict-free b128 reads
#define SST 72    // Ss/Vs LDS stride: bank-start 4e%32 -> conflict-free b128 reads

typedef unsigned short u16;
typedef __attribute__((ext_vector_type(4))) float f32x4;
typedef __attribute__((ext_vector_type(8))) __bf16 bf16x8;
typedef __attribute__((ext_vector_type(8))) u16 u16x8;
typedef __attribute__((ext_vector_type(4))) u16 u16x4;

union FragU { u16x8 u; bf16x8 b; };

__device__ __forceinline__ u16 f2bf(float f) {
  union { float f; unsigned u; } x; x.f = f;
  return (u16)((x.u + 0x7FFFu + ((x.u >> 16) & 1u)) >> 16);  // RNE
}
__device__ __forceinline__ float bf2f(u16 h) {
  union { unsigned u; float f; } x; x.u = ((unsigned)h) << 16;
  return x.f;
}

// One 192x192 (W, bf16) @ 192xTN (x, fp32->bf16) GEMM into per-wave acc[3][4] tiles.
// Wave w owns output rows [48w, 48w+48). MFMA 16x16x32 bf16.
// A-frag: lane holds A[row = l&15][k = (l>>4)*8 + j]; B-frag: B[k=(l>>4)*8+j][col=l&15].
// D: row = (l>>4)*4 + reg, col = l&15  (guide-verified layout).
__device__ __forceinline__ void gemm_stage_compute(
    const float* __restrict__ xb, const u16* __restrict__ Wp,
    int t0, int tid, f32x4 acc[3][4], u16 (*Xs)[XST])
{
  const int lg = (tid >> 4) & 3, lc = tid & 15;
  const int wave = tid >> 6, e0 = wave * 48;
  const int sn = tid & 63, scg = tid >> 6;
#pragma unroll
  for (int et = 0; et < 3; ++et)
#pragma unroll
    for (int nt = 0; nt < 4; ++nt)
      acc[et][nt] = f32x4{0.f, 0.f, 0.f, 0.f};

#pragma unroll
  for (int hf = 0; hf < 2; ++hf) {
    // stage X half (96 channels) transposed into Xs[n][c]; 4 strided coalesced
    // dword loads -> packed b64 LDS write
#pragma unroll
    for (int i = 0; i < 6; ++i) {
      int cl = scg * 4 + i * 16;
      const float* src = xb + (size_t)(hf * 96 + cl) * NN + t0 + sn;
      u16x4 p;
      p[0] = f2bf(src[0]);
      p[1] = f2bf(src[NN]);
      p[2] = f2bf(src[2 * NN]);
      p[3] = f2bf(src[3 * NN]);
      *reinterpret_cast<u16x4*>(&Xs[sn][cl]) = p;
    }
    __syncthreads();
#pragma unroll
    for (int ks = 0; ks < 3; ++ks) {
      FragU a[3], bb[4];
#pragma unroll
      for (int et = 0; et < 3; ++et)
        a[et].u = *reinterpret_cast<const u16x8*>(
            &Wp[(e0 + et * 16 + lc) * 192 + hf * 96 + ks * 32 + lg * 8]);
#pragma unroll
      for (int nt = 0; nt < 4; ++nt)
        bb[nt].u = *reinterpret_cast<const u16x8*>(&Xs[nt * 16 + lc][ks * 32 + lg * 8]);
#pragma unroll
      for (int et = 0; et < 3; ++et)
#pragma unroll
        for (int nt = 0; nt < 4; ++nt)
          acc[et][nt] = __builtin_amdgcn_mfma_f32_16x16x32_bf16(a[et].b, bb[nt].b,
                                                               acc[et][nt], 0, 0, 0);
    }
    __syncthreads();
  }
}

// Fused projections: k-proj->exp->Ss + ksum atomics; v-proj->Vs; per-wave ctx MFMA
// (2 heads/wave) with atomicAdd into ctx_num; q-proj->Ss; q-softmax over d; write qs bf16.
__global__ __launch_bounds__(256, 2)
void kp(const float* __restrict__ q, const float* __restrict__ k, const float* __restrict__ v,
        const u16* __restrict__ Wb,
        const float* __restrict__ bq, const float* __restrict__ bk, const float* __restrict__ bv,
        u16* __restrict__ qs, float* __restrict__ ctx, float* __restrict__ ksum)
{
  __shared__ __align__(16) u16 Xs[TN][XST];
  __shared__ __align__(16) u16 Ss[192][SST];
  __shared__ __align__(16) u16 Vs[192][SST];

  const int b = blockIdx.y;
  const int t0 = blockIdx.x * TN;
  const int tid = threadIdx.x;
  const int lg = (tid >> 4) & 3, lc = tid & 15;
  const int wave = tid >> 6, e0 = wave * 48;

  f32x4 acc[3][4];

  // ---- K projection: exp, stage to Ss, ksum atomics ----
  gemm_stage_compute(k + (size_t)b * CC * NN, Wb + 36864, t0, tid, acc, Xs);
#pragma unroll
  for (int et = 0; et < 3; ++et)
#pragma unroll
    for (int r = 0; r < 4; ++r) {
      int e = e0 + et * 16 + lg * 4 + r;
      float bias = bk[e];
      float sum = 0.f;
#pragma unroll
      for (int nt = 0; nt < 4; ++nt) {
        float val = __expf(acc[et][nt][r] + bias);  // |kp| <~ 2.5, no max needed
        Ss[e][nt * 16 + lc] = f2bf(val);
        sum += val;
      }
      sum += __shfl_xor(sum, 1);
      sum += __shfl_xor(sum, 2);
      sum += __shfl_xor(sum, 4);
      sum += __shfl_xor(sum, 8);
      if (lc == 0) atomicAdd(&ksum[(b * 8 + e / 24) * 24 + (e % 24)], sum);
    }

  // ---- V projection: stage to Vs ----
  gemm_stage_compute(v + (size_t)b * CC * NN, Wb + 2 * 36864, t0, tid, acc, Xs);
#pragma unroll
  for (int et = 0; et < 3; ++et)
#pragma unroll
    for (int r = 0; r < 4; ++r) {
      int e = e0 + et * 16 + lg * 4 + r;
      float bias = bv[e];
#pragma unroll
      for (int nt = 0; nt < 4; ++nt)
        Vs[e][nt * 16 + lc] = f2bf(acc[et][nt][r] + bias);
    }
  __syncthreads();  // Ss/Vs complete across all waves

  // ---- ctx accumulation: ctxT[dv][d] = sum_n V[dv][n]*S[d][n]; wave handles 2 heads ----
  {
    f32x4 cacc[2][2][2];
#pragma unroll
    for (int hi = 0; hi < 2; ++hi)
#pragma unroll
      for (int mt = 0; mt < 2; ++mt)
#pragma unroll
        for (int nt = 0; nt < 2; ++nt) cacc[hi][mt][nt] = f32x4{0.f, 0.f, 0.f, 0.f};
#pragma unroll
    for (int hi = 0; hi < 2; ++hi) {
      const int base = (wave * 2 + hi) * 24;
#pragma unroll
      for (int ks = 0; ks < 2; ++ks) {
        FragU av[2], bs[2];
#pragma unroll
        for (int mt = 0; mt < 2; ++mt) {
          int row = base + mt * 16 + lc;         // d=24 padded to 32; rows >=24 discarded
          if (row > 191) row = 191;              // keep in-bounds (head 7 only)
          av[mt].u = *reinterpret_cast<const u16x8*>(&Vs[row][ks * 32 + lg * 8]);
          bs[mt].u = *reinterpret_cast<const u16x8*>(&Ss[row][ks * 32 + lg * 8]);
        }
#pragma unroll
        for (int mt = 0; mt < 2; ++mt)
#pragma unroll
          for (int nt = 0; nt < 2; ++nt)
            cacc[hi][mt][nt] = __builtin_amdgcn_mfma_f32_16x16x32_bf16(
                av[mt].b, bs[nt].b, cacc[hi][mt][nt], 0, 0, 0);
      }
    }
#pragma unroll
    for (int hi = 0; hi < 2; ++hi)
#pragma unroll
      for (int mt = 0; mt < 2; ++mt)
#pragma unroll
        for (int nt = 0; nt < 2; ++nt)
#pragma unroll
          for (int r = 0; r < 4; ++r) {
            int dv = mt * 16 + lg * 4 + r;
            int d = nt * 16 + lc;
            if (dv < 24 && d < 24) {
              int h = wave * 2 + hi;
              atomicAdd(&ctx[((b * 8 + h) * 24 + d) * 24 + dv], cacc[hi][mt][nt][r]);
            }
          }
  }

  // ---- Q projection: stage to Ss (reuse; all waves past ctx by q-gemm's first barrier) ----
  gemm_stage_compute(q + (size_t)b * CC * NN, Wb, t0, tid, acc, Xs);
#pragma unroll
  for (int et = 0; et < 3; ++et)
#pragma unroll
    for (int r = 0; r < 4; ++r) {
      int e = e0 + et * 16 + lg * 4 + r;
      float bias = bq[e];
#pragma unroll
      for (int nt = 0; nt < 4; ++nt)
        Ss[e][nt * 16 + lc] = f2bf(acc[et][nt][r] + bias);
    }
  __syncthreads();

  // ---- Q softmax over d (24) per (token, head); write qs bf16 [b][e][n] ----
  {
    const int n = tid & 63;
    const int hb = tid >> 6;
#pragma unroll
    for (int hh = 0; hh < 2; ++hh) {
      const int h = hb + hh * 4;
      float vals[24];
      float m = -1e30f;
#pragma unroll
      for (int d = 0; d < 24; ++d) {
        vals[d] = bf2f(Ss[h * 24 + d][n]);
        m = fmaxf(m, vals[d]);
      }
      float s = 0.f;
#pragma unroll
      for (int d = 0; d < 24; ++d) { vals[d] = __expf(vals[d] - m); s += vals[d]; }
      const float inv = 1.f / s;
#pragma unroll
      for (int d = 0; d < 24; ++d)
        qs[(size_t)(b * 192 + h * 24 + d) * NN + t0 + n] = f2bf(vals[d] * inv);
    }
  }
}

// Meff[b][o][h*24+d] = sum_dv Wo[o][h*24+dv] * ctx_num[b][h][d][dv] / ksum[b][h][d]
__global__ void km(const float* __restrict__ Wo, const float* __restrict__ ctx,
                   const float* __restrict__ ksum, u16* __restrict__ Meff)
{
  const int o = blockIdx.x, b = blockIdx.y, j = threadIdx.x;
  const int h = j / 24, d = j % 24;
  const float* Wrow = Wo + o * 192 + h * 24;
  const float* crow = ctx + ((b * 8 + h) * 24 + d) * 24;
  float acc = 0.f;
#pragma unroll
  for (int dv = 0; dv < 24; ++dv) acc += Wrow[dv] * crow[dv];
  acc /= ksum[(b * 8 + h) * 24 + d];
  Meff[(b * 192 + o) * 192 + j] = f2bf(acc);
}

// out[b] = Meff[b] @ qs[b] + bo   (192 x 16384 x 192 GEMM, fp32 out)
__global__ __launch_bounds__(256, 2)
void ko(const u16* __restrict__ qs, const u16* __restrict__ Meff,
        const float* __restrict__ bo, float* __restrict__ out)
{
  __shared__ __align__(16) u16 Bs[TN][XST];
  const int b = blockIdx.y;
  const int t0 = blockIdx.x * TN;
  const int tid = threadIdx.x;
  const int lg = (tid >> 4) & 3, lc = tid & 15;
  const int wave = tid >> 6, e0 = wave * 48;
  const int sn = tid & 63, scg = tid >> 6;
  const u16* Mb = Meff + b * 36864;

  f32x4 acc[3][4];
#pragma unroll
  for (int et = 0; et < 3; ++et)
#pragma unroll
    for (int nt = 0; nt < 4; ++nt) acc[et][nt] = f32x4{0.f, 0.f, 0.f, 0.f};

#pragma unroll
  for (int hf = 0; hf < 2; ++hf) {
#pragma unroll
    for (int i = 0; i < 6; ++i) {
      int jl = scg * 4 + i * 16;
      const u16* src = qs + (size_t)(b * 192 + hf * 96 + jl) * NN + t0 + sn;
      u16x4 p;
      p[0] = src[0]; p[1] = src[NN]; p[2] = src[2 * NN]; p[3] = src[3 * NN];
      *reinterpret_cast<u16x4*>(&Bs[sn][jl]) = p;
    }
    __syncthreads();
#pragma unroll
    for (int ks = 0; ks < 3; ++ks) {
      FragU a[3], bb[4];
#pragma unroll
      for (int et = 0; et < 3; ++et)
        a[et].u = *reinterpret_cast<const u16x8*>(
            &Mb[(e0 + et * 16 + lc) * 192 + hf * 96 + ks * 32 + lg * 8]);
#pragma unroll
      for (int nt = 0; nt < 4; ++nt)
        bb[nt].u = *reinterpret_cast<const u16x8*>(&Bs[nt * 16 + lc][ks * 32 + lg * 8]);
#pragma unroll
      for (int et = 0; et < 3; ++et)
#pragma unroll
        for (int nt = 0; nt < 4; ++nt)
          acc[et][nt] = __builtin_amdgcn_mfma_f32_16x16x32_bf16(a[et].b, bb[nt].b,
                                                               acc[et][nt], 0, 0, 0);
    }
    __syncthreads();
  }

#pragma unroll
  for (int et = 0; et < 3; ++et)
#pragma unroll
    for (int r = 0; r < 4; ++r) {
      int row = e0 + et * 16 + lg * 4 + r;
      float bias = bo[row];
#pragma unroll
      for (int nt = 0; nt < 4; ++nt)
        out[(size_t)(b * 192 + row) * NN + t0 + nt * 16 + lc] = acc[et][nt][r] + bias;
    }
}

// Convert Wq/Wk/Wv to bf16 (packed [3][192][192]); zero ctx_num+ksum (19200 floats).
__global__ void kz(const float* __restrict__ Wq, const float* __restrict__ Wk,
                   const float* __restrict__ Wv, u16* __restrict__ Wb,
                   float* __restrict__ zero_region)
{
  const int i = blockIdx.x * 256 + threadIdx.x;
  if (i < 110592) {
    const float* src = (i < 36864) ? Wq : (i < 73728) ? Wk : Wv;
    Wb[i] = f2bf(src[i % 36864]);
  }
  if (i < 19200) zero_region[i] = 0.f;
}

extern "C" void kernel_launch(void* const* d_in, const int* in_sizes, int n_in,
                              void* d_out, int out_size, void* d_ws, size_t ws_size,
                              hipStream_t stream)
{
  const float* q  = (const float*)d_in[0];
  const float* k  = (const float*)d_in[1];
  const float* v  = (const float*)d_in[2];
  const float* Wq = (const float*)d_in[3];
  const float* bq = (const float*)d_in[4];
  const float* Wk = (const float*)d_in[5];
  const float* bk = (const float*)d_in[6];
  const float* Wv = (const float*)d_in[7];
  const float* bv = (const float*)d_in[8];
  const float* Wo = (const float*)d_in[9];
  const float* bo = (const float*)d_in[10];
  float* out = (float*)d_out;

  // workspace carve (all offsets 256B-aligned); total ~25.8 MB
  char* w = (char*)d_ws;
  u16*   Wb   = (u16*)(w);               // 221184 B : [3][192][192] bf16
  float* ctx  = (float*)(w + 221184);    // 73728 B  : [4][8][24][24] fp32 (ctx_num)
  float* ksum = (float*)(w + 294912);    // 3072 B   : [4][8][24] fp32
  u16*   Meff = (u16*)(w + 297984);      // 294912 B : [4][192][192] bf16
  u16*   qs   = (u16*)(w + 592896);      // 25165824 B : [4][192][16384] bf16

  hipLaunchKernelGGL(kz, dim3(432), dim3(256), 0, stream, Wq, Wk, Wv, Wb, ctx);
  hipLaunchKernelGGL(kp, dim3(256, 4), dim3(256), 0, stream, q, k, v, Wb, bq, bk, bv,
                     qs, ctx, ksum);
  hipLaunchKernelGGL(km, dim3(192, 4), dim3(192), 0, stream, Wo, ctx, ksum, Meff);
  hipLaunchKernelGGL(ko, dim3(256, 4), dim3(256), 0, stream, qs, Meff, bo, out);
}

// Round 2
// 133.242 us; speedup vs baseline: 2.1205x; 2.1205x over previous
//
#include <hip/hip_runtime.h>

#define CC 192
#define NN 16384
#define TN 64
#define XST 104   // Xs LDS stride (elements)
#define SST 72    // Ss/Vs LDS stride (elements)
#define QST 200   // SsT LDS stride (elements) in kq

typedef unsigned short u16;
typedef __attribute__((ext_vector_type(4))) float f32x4;
typedef __attribute__((ext_vector_type(8))) __bf16 bf16x8;
typedef __attribute__((ext_vector_type(8))) u16 u16x8;
typedef __attribute__((ext_vector_type(4))) u16 u16x4;

union FragU { u16x8 u; bf16x8 b; };

__device__ __forceinline__ u16 f2bf(float f) {
  union { float f; unsigned u; } x; x.f = f;
  return (u16)((x.u + 0x7FFFu + ((x.u >> 16) & 1u)) >> 16);  // RNE
}
__device__ __forceinline__ float bf2f(u16 h) {
  union { unsigned u; float f; } x; x.u = ((unsigned)h) << 16;
  return x.f;
}

// One 192x192 (W, bf16) @ 192xTN (x, fp32->bf16) GEMM into per-wave acc[3][4].
// Wave w owns output rows [48w, 48w+48). MFMA 16x16x32 bf16.
__device__ __forceinline__ void gemm_stage_compute(
    const float* __restrict__ xb, const u16* __restrict__ Wp,
    int t0, int tid, f32x4 acc[3][4], u16 (*Xs)[XST])
{
  const int lg = (tid >> 4) & 3, lc = tid & 15;
  const int wave = tid >> 6, e0 = wave * 48;
  const int sn = tid & 63, scg = tid >> 6;
#pragma unroll
  for (int et = 0; et < 3; ++et)
#pragma unroll
    for (int nt = 0; nt < 4; ++nt)
      acc[et][nt] = f32x4{0.f, 0.f, 0.f, 0.f};

#pragma unroll
  for (int hf = 0; hf < 2; ++hf) {
#pragma unroll
    for (int i = 0; i < 6; ++i) {
      int cl = scg * 4 + i * 16;
      const float* src = xb + (size_t)(hf * 96 + cl) * NN + t0 + sn;
      u16x4 p;
      p[0] = f2bf(src[0]);
      p[1] = f2bf(src[NN]);
      p[2] = f2bf(src[2 * NN]);
      p[3] = f2bf(src[3 * NN]);
      *reinterpret_cast<u16x4*>(&Xs[sn][cl]) = p;
    }
    __syncthreads();
#pragma unroll
    for (int ks = 0; ks < 3; ++ks) {
      FragU a[3], bb[4];
#pragma unroll
      for (int et = 0; et < 3; ++et)
        a[et].u = *reinterpret_cast<const u16x8*>(
            &Wp[(e0 + et * 16 + lc) * 192 + hf * 96 + ks * 32 + lg * 8]);
#pragma unroll
      for (int nt = 0; nt < 4; ++nt)
        bb[nt].u = *reinterpret_cast<const u16x8*>(&Xs[nt * 16 + lc][ks * 32 + lg * 8]);
#pragma unroll
      for (int et = 0; et < 3; ++et)
#pragma unroll
        for (int nt = 0; nt < 4; ++nt)
          acc[et][nt] = __builtin_amdgcn_mfma_f32_16x16x32_bf16(a[et].b, bb[nt].b,
                                                               acc[et][nt], 0, 0, 0);
    }
    __syncthreads();
  }
}

// KV kernel: per block, 2 token tiles. k-proj->exp->Ss + ksum reg-accum;
// v-proj->Vs; ctx MFMA accumulated in registers; NON-ATOMIC partial stores.
__global__ __launch_bounds__(256, 2)
void kv(const float* __restrict__ k, const float* __restrict__ v,
        const u16* __restrict__ Wb,
        const float* __restrict__ bk, const float* __restrict__ bv,
        float* __restrict__ ctxpart, float* __restrict__ ksumpart)
{
  __shared__ __align__(16) u16 Xs[TN][XST];
  __shared__ __align__(16) u16 Ss[192][SST];
  __shared__ __align__(16) u16 Vs[192][SST];

  const int b = blockIdx.y;
  const int blk = blockIdx.x;      // 0..127
  const int tid = threadIdx.x;
  const int lg = (tid >> 4) & 3, lc = tid & 15;
  const int wave = tid >> 6, e0 = wave * 48;

  f32x4 acc[3][4];
  f32x4 cacc[2][2][2];
  float ksum_r[3][4];
#pragma unroll
  for (int hi = 0; hi < 2; ++hi)
#pragma unroll
    for (int mt = 0; mt < 2; ++mt)
#pragma unroll
      for (int nt = 0; nt < 2; ++nt) cacc[hi][mt][nt] = f32x4{0.f, 0.f, 0.f, 0.f};
#pragma unroll
  for (int et = 0; et < 3; ++et)
#pragma unroll
    for (int r = 0; r < 4; ++r) ksum_r[et][r] = 0.f;

  for (int it = 0; it < 2; ++it) {
    const int t0 = (blk * 2 + it) * TN;

    // ---- K projection -> exp -> Ss; token-sum into registers ----
    gemm_stage_compute(k + (size_t)b * CC * NN, Wb + 36864, t0, tid, acc, Xs);
#pragma unroll
    for (int et = 0; et < 3; ++et)
#pragma unroll
      for (int r = 0; r < 4; ++r) {
        int e = e0 + et * 16 + lg * 4 + r;
        float bias = bk[e];
        float sum = 0.f;
#pragma unroll
        for (int nt = 0; nt < 4; ++nt) {
          float val = __expf(acc[et][nt][r] + bias);  // |kp| small, no max needed
          Ss[e][nt * 16 + lc] = f2bf(val);
          sum += val;
        }
        sum += __shfl_xor(sum, 1);
        sum += __shfl_xor(sum, 2);
        sum += __shfl_xor(sum, 4);
        sum += __shfl_xor(sum, 8);
        ksum_r[et][r] += sum;
      }

    // ---- V projection -> Vs ----
    gemm_stage_compute(v + (size_t)b * CC * NN, Wb + 2 * 36864, t0, tid, acc, Xs);
#pragma unroll
    for (int et = 0; et < 3; ++et)
#pragma unroll
      for (int r = 0; r < 4; ++r) {
        int e = e0 + et * 16 + lg * 4 + r;
        float bias = bv[e];
#pragma unroll
        for (int nt = 0; nt < 4; ++nt)
          Vs[e][nt * 16 + lc] = f2bf(acc[et][nt][r] + bias);
      }
    __syncthreads();  // Ss/Vs complete across all waves

    // ---- ctx accumulation: ctxT[dv][d] += sum_n V[dv][n]*S[d][n]; 2 heads/wave ----
#pragma unroll
    for (int hi = 0; hi < 2; ++hi) {
      const int base = (wave * 2 + hi) * 24;
#pragma unroll
      for (int ks = 0; ks < 2; ++ks) {
        FragU av[2], bs[2];
#pragma unroll
        for (int mt = 0; mt < 2; ++mt) {
          int row = base + mt * 16 + lc;   // d padded 24->32; extra rows discarded
          if (row > 191) row = 191;
          av[mt].u = *reinterpret_cast<const u16x8*>(&Vs[row][ks * 32 + lg * 8]);
          bs[mt].u = *reinterpret_cast<const u16x8*>(&Ss[row][ks * 32 + lg * 8]);
        }
#pragma unroll
        for (int mt = 0; mt < 2; ++mt)
#pragma unroll
          for (int nt = 0; nt < 2; ++nt)
            cacc[hi][mt][nt] = __builtin_amdgcn_mfma_f32_16x16x32_bf16(
                av[mt].b, bs[nt].b, cacc[hi][mt][nt], 0, 0, 0);
      }
    }
    __syncthreads();  // ctx MFMA done reading Ss/Vs before next iteration overwrites
  }

  // ---- non-atomic partial stores ----
  const int pb = b * 128 + blk;
#pragma unroll
  for (int hi = 0; hi < 2; ++hi)
#pragma unroll
    for (int mt = 0; mt < 2; ++mt)
#pragma unroll
      for (int nt = 0; nt < 2; ++nt)
#pragma unroll
        for (int r = 0; r < 4; ++r) {
          int dv = mt * 16 + lg * 4 + r;
          int d = nt * 16 + lc;
          if (dv < 24 && d < 24) {
            int h = wave * 2 + hi;
            ctxpart[(size_t)(pb * 8 + h) * 576 + d * 24 + dv] = cacc[hi][mt][nt][r];
          }
        }
  if (lc == 0) {
#pragma unroll
    for (int et = 0; et < 3; ++et)
#pragma unroll
      for (int r = 0; r < 4; ++r) {
        int e = e0 + et * 16 + lg * 4 + r;
        ksumpart[(size_t)pb * 192 + e] = ksum_r[et][r];
      }
  }
}

// Reduce partials: ctx[b][h][d][dv] = (sum_i ctxpart) / (sum_i ksumpart)
__global__ void kr(const float* __restrict__ ctxpart, const float* __restrict__ ksumpart,
                   float* __restrict__ ctx)
{
  const int id = blockIdx.x * 256 + threadIdx.x;
  if (id >= 4 * 4608) return;
  const int b = id / 4608, r = id % 4608;
  const int h = r / 576, rem = r % 576;
  const int d = rem / 24, dv = rem % 24;
  float s1 = 0.f, s2 = 0.f;
  for (int i = 0; i < 128; ++i) {
    s1 += ctxpart[(size_t)((b * 128 + i) * 8 + h) * 576 + d * 24 + dv];
    s2 += ksumpart[(size_t)(b * 128 + i) * 192 + h * 24 + d];
  }
  ctx[((b * 8 + h) * 24 + d) * 24 + dv] = s1 / s2;
}

// Meff[b][o][h*24+d] = sum_dv Wo[o][h*24+dv] * ctx[b][h][d][dv]   (ctx pre-normalized)
__global__ void km(const float* __restrict__ Wo, const float* __restrict__ ctx,
                   u16* __restrict__ Meff)
{
  const int o = blockIdx.x, b = blockIdx.y, j = threadIdx.x;
  const int h = j / 24, d = j % 24;
  const float* Wrow = Wo + o * 192 + h * 24;
  const float* crow = ctx + ((b * 8 + h) * 24 + d) * 24;
  float acc = 0.f;
#pragma unroll
  for (int dv = 0; dv < 24; ++dv) acc += Wrow[dv] * crow[dv];
  Meff[(b * 192 + o) * 192 + j] = f2bf(acc);
}

// Q kernel: q-proj -> SsT[n][e] -> softmax over d -> Meff GEMM -> out (+bo). Fused.
__global__ __launch_bounds__(256, 4)
void kq(const float* __restrict__ q, const u16* __restrict__ Wb,
        const float* __restrict__ bq, const u16* __restrict__ Meff,
        const float* __restrict__ bo, float* __restrict__ out)
{
  __shared__ __align__(16) u16 Xs[TN][XST];
  __shared__ __align__(16) u16 SsT[TN][QST];

  const int b = blockIdx.y;
  const int t0 = blockIdx.x * TN;
  const int tid = threadIdx.x;
  const int lg = (tid >> 4) & 3, lc = tid & 15;
  const int wave = tid >> 6, e0 = wave * 48;
  const u16* Mb = Meff + b * 36864;

  f32x4 acc[3][4];

  // ---- Q projection ----
  gemm_stage_compute(q + (size_t)b * CC * NN, Wb, t0, tid, acc, Xs);
#pragma unroll
  for (int et = 0; et < 3; ++et)
#pragma unroll
    for (int r = 0; r < 4; ++r) {
      int e = e0 + et * 16 + lg * 4 + r;
      float bias = bq[e];
#pragma unroll
      for (int nt = 0; nt < 4; ++nt)
        SsT[nt * 16 + lc][e] = f2bf(acc[et][nt][r] + bias);
    }
  __syncthreads();

  // ---- softmax over d (24) per (token, head), in-place on SsT ----
#pragma unroll
  for (int ii = 0; ii < 2; ++ii) {
    const int item = ii * 256 + tid;
    const int n = item & 63, h = item >> 6;
    u16* rowp = &SsT[n][h * 24];
    float vals[24];
    float m = -1e30f;
#pragma unroll
    for (int d = 0; d < 24; ++d) {
      vals[d] = bf2f(rowp[d]);
      m = fmaxf(m, vals[d]);
    }
    float s = 0.f;
#pragma unroll
    for (int d = 0; d < 24; ++d) { vals[d] = __expf(vals[d] - m); s += vals[d]; }
    const float inv = 1.f / s;
#pragma unroll
    for (int d = 0; d < 24; ++d) rowp[d] = f2bf(vals[d] * inv);
  }
  __syncthreads();

  // ---- Meff GEMM: out_rows = Meff (192x192) @ SsT^T (192 x 64) ----
#pragma unroll
  for (int et = 0; et < 3; ++et)
#pragma unroll
    for (int nt = 0; nt < 4; ++nt) acc[et][nt] = f32x4{0.f, 0.f, 0.f, 0.f};
#pragma unroll
  for (int ks = 0; ks < 6; ++ks) {
    FragU a[3], bb[4];
#pragma unroll
    for (int et = 0; et < 3; ++et)
      a[et].u = *reinterpret_cast<const u16x8*>(
          &Mb[(e0 + et * 16 + lc) * 192 + ks * 32 + lg * 8]);
#pragma unroll
    for (int nt = 0; nt < 4; ++nt)
      bb[nt].u = *reinterpret_cast<const u16x8*>(&SsT[nt * 16 + lc][ks * 32 + lg * 8]);
#pragma unroll
    for (int et = 0; et < 3; ++et)
#pragma unroll
      for (int nt = 0; nt < 4; ++nt)
        acc[et][nt] = __builtin_amdgcn_mfma_f32_16x16x32_bf16(a[et].b, bb[nt].b,
                                                             acc[et][nt], 0, 0, 0);
  }

  // ---- epilogue: + bo, fp32 stores ----
#pragma unroll
  for (int et = 0; et < 3; ++et)
#pragma unroll
    for (int r = 0; r < 4; ++r) {
      int row = e0 + et * 16 + lg * 4 + r;
      float bias = bo[row];
#pragma unroll
      for (int nt = 0; nt < 4; ++nt)
        out[(size_t)(b * 192 + row) * NN + t0 + nt * 16 + lc] = acc[et][nt][r] + bias;
    }
}

// Convert Wq/Wk/Wv to bf16 (packed [3][192][192]).
__global__ void kz(const float* __restrict__ Wq, const float* __restrict__ Wk,
                   const float* __restrict__ Wv, u16* __restrict__ Wb)
{
  const int i = blockIdx.x * 256 + threadIdx.x;
  if (i < 110592) {
    const float* src = (i < 36864) ? Wq : (i < 73728) ? Wk : Wv;
    Wb[i] = f2bf(src[i % 36864]);
  }
}

extern "C" void kernel_launch(void* const* d_in, const int* in_sizes, int n_in,
                              void* d_out, int out_size, void* d_ws, size_t ws_size,
                              hipStream_t stream)
{
  const float* q  = (const float*)d_in[0];
  const float* k  = (const float*)d_in[1];
  const float* v  = (const float*)d_in[2];
  const float* Wq = (const float*)d_in[3];
  const float* bq = (const float*)d_in[4];
  const float* Wk = (const float*)d_in[5];
  const float* bk = (const float*)d_in[6];
  const float* Wv = (const float*)d_in[7];
  const float* bv = (const float*)d_in[8];
  const float* Wo = (const float*)d_in[9];
  const float* bo = (const float*)d_in[10];
  float* out = (float*)d_out;

  // workspace carve (256B-aligned); total ~10.4 MB
  char* w = (char*)d_ws;
  u16*   Wb       = (u16*)(w);                  // 221184 B : [3][192][192] bf16
  float* ctxpart  = (float*)(w + 221184);       // 9437184 B : [4*128][8][24][24]
  float* ksumpart = (float*)(w + 9658368);      // 393216 B : [4*128][192]
  float* ctx      = (float*)(w + 10051584);     // 73728 B : [4][8][24][24]
  u16*   Meff     = (u16*)(w + 10125312);       // 294912 B : [4][192][192] bf16

  hipLaunchKernelGGL(kz, dim3(432), dim3(256), 0, stream, Wq, Wk, Wv, Wb);
  hipLaunchKernelGGL(kv, dim3(128, 4), dim3(256), 0, stream, k, v, Wb, bk, bv,
                     ctxpart, ksumpart);
  hipLaunchKernelGGL(kr, dim3(72), dim3(256), 0, stream, ctxpart, ksumpart, ctx);
  hipLaunchKernelGGL(km, dim3(192, 4), dim3(192), 0, stream, Wo, ctx, Meff);
  hipLaunchKernelGGL(kq, dim3(256, 4), dim3(256), 0, stream, q, Wb, bq, Meff, bo, out);
}